// Round 1
// baseline (1675.941 us; speedup 1.0000x reference)
//
#include <hip/hip_runtime.h>

// Multi-scale warp: out[b,c,i,j] = bilinear_sample(img[b,c], y(b,i,j), x(b,i,j))
// with x from grid ch0 = -1 + (i-1)/(S-1)*2 + flow[b,0,i,j]  (row idx -> x!)
//      y from grid ch1 = -1 + (j-1)/(S-1)*2 + flow[b,1,i,j]
// zeros padding, align_corners=True. Faithful to reference incl. (i-1) offset.

template <int S, int C>
__global__ __launch_bounds__(256) void warp_kernel(
    const float* __restrict__ img, const float* __restrict__ flow,
    float* __restrict__ out, int total)
{
    constexpr int SS = S * S;
    int idx = blockIdx.x * blockDim.x + threadIdx.x;   // over B*S*S
    if (idx >= total) return;

    const int b   = idx / SS;          // power-of-2 -> shifts
    const int rem = idx - b * SS;      // i*S + j
    const int i   = rem / S;
    const int j   = rem - i * S;

    // flow loads: coalesced (consecutive threads -> consecutive j)
    const float f0 = flow[(size_t)b * 2 * SS + rem];        // channel 0
    const float f1 = flow[(size_t)b * 2 * SS + SS + rem];   // channel 1

    const float sm1 = (float)(S - 1);
    // match reference op order: -1 + (idx-1)/(S-1)*2 + flow; then (g+1)*0.5*(S-1)
    const float gx = -1.0f + ((float)i - 1.0f) / sm1 * 2.0f + f0;
    const float gy = -1.0f + ((float)j - 1.0f) / sm1 * 2.0f + f1;
    const float x = (gx + 1.0f) * 0.5f * sm1;
    const float y = (gy + 1.0f) * 0.5f * sm1;

    const float x0f = floorf(x), y0f = floorf(y);
    const float x1f = x0f + 1.0f, y1f = y0f + 1.0f;
    const float wx1 = x - x0f, wx0 = 1.0f - wx1;
    const float wy1 = y - y0f, wy0 = 1.0f - wy1;

    const bool bx0 = (x0f >= 0.0f) && (x0f <= sm1);
    const bool bx1 = (x1f >= 0.0f) && (x1f <= sm1);
    const bool by0 = (y0f >= 0.0f) && (y0f <= sm1);
    const bool by1 = (y1f >= 0.0f) && (y1f <= sm1);

    const int xc0 = (int)fminf(fmaxf(x0f, 0.0f), sm1);
    const int xc1 = (int)fminf(fmaxf(x1f, 0.0f), sm1);
    const int yc0 = (int)fminf(fmaxf(y0f, 0.0f), sm1);
    const int yc1 = (int)fminf(fmaxf(y1f, 0.0f), sm1);

    // fold zero-padding mask into the 4 tap weights (no divergence)
    const float w00 = (by0 && bx0) ? wy0 * wx0 : 0.0f;
    const float w01 = (by0 && bx1) ? wy0 * wx1 : 0.0f;
    const float w10 = (by1 && bx0) ? wy1 * wx0 : 0.0f;
    const float w11 = (by1 && bx1) ? wy1 * wx1 : 0.0f;

    const int o00 = yc0 * S + xc0;
    const int o01 = yc0 * S + xc1;
    const int o10 = yc1 * S + xc0;
    const int o11 = yc1 * S + xc1;

    const float* ib = img + (size_t)b * C * SS;
    float*       ob = out + (size_t)b * C * SS + rem;

    // unroll-4: ~16 gathers in flight, keeps VGPR pressure moderate
    #pragma unroll 4
    for (int c = 0; c < C; ++c) {
        const float* p = ib + (size_t)c * SS;
        float v = w00 * p[o00] + w01 * p[o01] + w10 * p[o10] + w11 * p[o11];
        ob[(size_t)c * SS] = v;   // coalesced per-channel store
    }
}

extern "C" void kernel_launch(void* const* d_in, const int* in_sizes, int n_in,
                              void* d_out, int out_size, void* d_ws, size_t ws_size,
                              hipStream_t stream) {
    constexpr int B = 16, C = 16;
    float* out = (float*)d_out;

    // inputs: img0, flow0, img1, flow1, img2, flow2, img3, flow3
    {
        constexpr int S = 512;
        int total = B * S * S;
        warp_kernel<S, C><<<total / 256, 256, 0, stream>>>(
            (const float*)d_in[0], (const float*)d_in[1], out, total);
        out += (size_t)B * C * S * S;
    }
    {
        constexpr int S = 256;
        int total = B * S * S;
        warp_kernel<S, C><<<total / 256, 256, 0, stream>>>(
            (const float*)d_in[2], (const float*)d_in[3], out, total);
        out += (size_t)B * C * S * S;
    }
    {
        constexpr int S = 128;
        int total = B * S * S;
        warp_kernel<S, C><<<total / 256, 256, 0, stream>>>(
            (const float*)d_in[4], (const float*)d_in[5], out, total);
        out += (size_t)B * C * S * S;
    }
    {
        constexpr int S = 64;
        int total = B * S * S;
        warp_kernel<S, C><<<total / 256, 256, 0, stream>>>(
            (const float*)d_in[6], (const float*)d_in[7], out, total);
        out += (size_t)B * C * S * S;
    }
}